// Round 1
// baseline (161.509 us; speedup 1.0000x reference)
//
#include <hip/hip_runtime.h>

#define ND 12
#define NN 1024
#define NS 4095
#define NK 32
#define NC 10

// ws layout (floats): [0..4095] cap_lookup indexed by bitmask; [4096..4111] latent accumulator

__global__ __launch_bounds__(64) void k_encoder(
    const float* __restrict__ X,
    const float* __restrict__ w1, const float* __restrict__ b1,
    const float* __restrict__ w2, const float* __restrict__ b2,
    const float* __restrict__ lng, const float* __restrict__ lnb,
    const float* __restrict__ w3, const float* __restrict__ b3,
    float* __restrict__ latacc)
{
    int lane = threadIdx.x;
    int row  = blockIdx.x * 64 + lane;

    float x[ND];
    #pragma unroll
    for (int d = 0; d < ND; ++d) x[d] = X[row * ND + d];

    float h1[32];
    #pragma unroll
    for (int o = 0; o < 32; ++o) {
        float a = b1[o];
        #pragma unroll
        for (int d = 0; d < ND; ++d) a += w1[o * ND + d] * x[d];
        h1[o] = fmaxf(a, 0.f);
    }

    float h2[16];
    #pragma unroll
    for (int o = 0; o < 16; ++o) {
        float a = b2[o];
        #pragma unroll
        for (int k = 0; k < 32; ++k) a += w2[o * 32 + k] * h1[k];
        h2[o] = fmaxf(a, 0.f);
    }

    float mu = 0.f;
    #pragma unroll
    for (int o = 0; o < 16; ++o) mu += h2[o];
    mu *= (1.f / 16.f);
    float var = 0.f;
    #pragma unroll
    for (int o = 0; o < 16; ++o) { float t = h2[o] - mu; var += t * t; }
    var *= (1.f / 16.f);
    float inv = 1.f / sqrtf(var + 1e-5f);

    float hn[16];
    #pragma unroll
    for (int o = 0; o < 16; ++o) hn[o] = (h2[o] - mu) * inv * lng[o] + lnb[o];

    float h3[16];
    #pragma unroll
    for (int o = 0; o < 16; ++o) {
        float a = b3[o];
        #pragma unroll
        for (int k = 0; k < 16; ++k) a += w3[o * 16 + k] * hn[k];
        h3[o] = a;
    }

    // wave-reduce each of the 16 components, one atomic per block per component
    #pragma unroll
    for (int o = 0; o < 16; ++o) {
        float v = h3[o];
        #pragma unroll
        for (int s = 1; s < 64; s <<= 1) v += __shfl_xor(v, s, 64);
        if (lane == 0) atomicAdd(&latacc[o], v);
    }
}

__global__ __launch_bounds__(1024) void k_caps(
    const float* __restrict__ latacc,
    const float* __restrict__ cw1, const float* __restrict__ cb1,
    const float* __restrict__ cw2, const float* __restrict__ cb2,
    float* __restrict__ cap_ws, float* __restrict__ out)
{
    __shared__ float arr[4096];
    int tid = threadIdx.x;

    float lat[16];
    #pragma unroll
    for (int k = 0; k < 16; ++k) lat[k] = latacc[k] * (1.f / 1024.f);

    float hc[16];
    #pragma unroll
    for (int o = 0; o < 16; ++o) {
        float a = cb1[o];
        #pragma unroll
        for (int k = 0; k < 16; ++k) a += cw1[o * 16 + k] * lat[k];
        hc[o] = fmaxf(a, 0.f);
    }

    // increments for subsets s (bitmask = s+1)
    #pragma unroll
    for (int r = 0; r < 4; ++r) {
        int s = tid * 4 + r;
        if (s < NS) {
            float a = cb2[s];
            #pragma unroll
            for (int k = 0; k < 16; ++k) a += cw2[s * 16 + k] * hc[k];
            arr[s + 1] = 0.1f / (1.f + expf(-a));   // sigmoid(a)*0.1
        }
    }
    if (tid == 0) arr[0] = 0.f;
    __syncthreads();

    // subset-sum (zeta transform) over 12 dims
    #pragma unroll 1
    for (int d = 0; d < ND; ++d) {
        int bit = 1 << d;
        #pragma unroll
        for (int r = 0; r < 2; ++r) {
            int i   = tid + r * 1024;          // 0..2047
            int low = i & (bit - 1);
            int m   = ((i >> d) << (d + 1)) | bit | low;
            arr[m] += arr[m ^ bit];
        }
        __syncthreads();
    }

    float denom = arr[4095] + 1e-8f;
    #pragma unroll
    for (int r = 0; r < 4; ++r) {
        int m   = tid * 4 + r;
        float c = arr[m] / denom;
        cap_ws[m] = c;
        if (m >= 1) out[NN * NC + m - 1] = c;   // caps output
    }
}

__global__ __launch_bounds__(256) void k_simvote(
    const float* __restrict__ X, const int* __restrict__ y,
    const float* __restrict__ cap_ws, float* __restrict__ out)
{
    __shared__ float cap[4096];
    __shared__ float rowsim[NN];
    int tid = threadIdx.x;
    int i   = blockIdx.x;

    #pragma unroll
    for (int t = 0; t < 16; ++t) cap[tid + 256 * t] = cap_ws[tid + 256 * t];

    float xi[ND];
    #pragma unroll
    for (int d = 0; d < ND; ++d) xi[d] = X[i * ND + d];
    __syncthreads();

    #pragma unroll 1
    for (int t = 0; t < 4; ++t) {
        int j = tid + 256 * t;
        float v[ND]; int b[ND];
        #pragma unroll
        for (int d = 0; d < ND; ++d) {
            v[d] = expf(-fabsf(xi[d] - X[j * ND + d]));
            b[d] = 1 << d;
        }
        // stable ascending bubble network (66 CEs, branchless, all static indices)
        #pragma unroll
        for (int p = 0; p < ND - 1; ++p) {
            #pragma unroll
            for (int q = 0; q < ND - 1 - p; ++q) {
                float a = v[q], c = v[q + 1];
                bool sw = a > c;
                v[q]     = sw ? c : a;
                v[q + 1] = sw ? a : c;
                int ba = b[q], bc = b[q + 1];
                b[q]     = sw ? bc : ba;
                b[q + 1] = sw ? ba : bc;
            }
        }
        // Choquet integral: sum_k (v[k]-v[k-1]) * cap[ OR b[k..11] ]
        int tail = 0; float sim = 0.f;
        #pragma unroll
        for (int k = ND - 1; k >= 0; --k) {
            tail |= b[k];
            float pv = (k > 0) ? v[k - 1] : 0.f;
            sim += (v[k] - pv) * cap[tail];
        }
        if (j == i) sim -= 1e9f;
        rowsim[j] = sim;
    }
    __syncthreads();

    if (tid < 64) {
        // wave 0: top-32 with jax.lax.top_k tie-break (lower index wins)
        unsigned long long key[16];
        #pragma unroll
        for (int t = 0; t < 16; ++t) {
            int j = tid + 64 * t;
            unsigned u = __float_as_uint(rowsim[j]);
            u = (u & 0x80000000u) ? ~u : (u | 0x80000000u);  // order-preserving map
            key[t] = (((unsigned long long)u) << 10) | (unsigned)(1023 - j);
        }
        float selval = 0.f; int selidx = 0;
        #pragma unroll 1
        for (int it = 0; it < NK; ++it) {
            unsigned long long loc = key[0];
            #pragma unroll
            for (int t = 1; t < 16; ++t) loc = (key[t] > loc) ? key[t] : loc;
            #pragma unroll
            for (int s = 1; s < 64; s <<= 1) {
                unsigned long long o = __shfl_xor(loc, s, 64);
                loc = (o > loc) ? o : loc;
            }
            #pragma unroll
            for (int t = 0; t < 16; ++t) if (key[t] == loc) key[t] = 0ull;
            if (tid == it) {
                unsigned su = (unsigned)(loc >> 10);
                unsigned ub = (su & 0x80000000u) ? (su & 0x7FFFFFFFu) : ~su;
                selval = __uint_as_float(ub);
                selidx = 1023 - (int)(loc & 1023ull);
            }
        }
        float vmax = __shfl(selval, 0, 64);
        float w = 0.f;
        if (tid < NK) w = expf((selval - vmax) * 2.0f);   // /TEMP with TEMP=0.5
        float sumw = w;
        #pragma unroll
        for (int s = 1; s < 64; s <<= 1) sumw += __shfl_xor(sumw, s, 64);
        float wt = w / sumw;
        int label = 0;
        if (tid < NK) label = y[selidx];
        #pragma unroll
        for (int c = 0; c < NC; ++c) {
            float vc = (tid < NK && label == c) ? wt : 0.f;
            #pragma unroll
            for (int s = 1; s < 64; s <<= 1) vc += __shfl_xor(vc, s, 64);
            if (tid == 0) out[i * NC + c] = vc;
        }
    }
}

extern "C" void kernel_launch(void* const* d_in, const int* in_sizes, int n_in,
                              void* d_out, int out_size, void* d_ws, size_t ws_size,
                              hipStream_t stream)
{
    const float* X   = (const float*)d_in[0];
    const int*   y   = (const int*)  d_in[1];
    const float* w1  = (const float*)d_in[2];
    const float* b1  = (const float*)d_in[3];
    const float* w2  = (const float*)d_in[4];
    const float* b2  = (const float*)d_in[5];
    const float* lng = (const float*)d_in[6];
    const float* lnb = (const float*)d_in[7];
    const float* w3  = (const float*)d_in[8];
    const float* b3  = (const float*)d_in[9];
    const float* cw1 = (const float*)d_in[10];
    const float* cb1 = (const float*)d_in[11];
    const float* cw2 = (const float*)d_in[12];
    const float* cb2 = (const float*)d_in[13];
    float* out = (float*)d_out;
    float* ws  = (float*)d_ws;

    float* cap_ws = ws;         // 4096 floats
    float* latacc = ws + 4096;  // 16 floats

    hipMemsetAsync(latacc, 0, 16 * sizeof(float), stream);
    k_encoder<<<16, 64, 0, stream>>>(X, w1, b1, w2, b2, lng, lnb, w3, b3, latacc);
    k_caps<<<1, 1024, 0, stream>>>(latacc, cw1, cb1, cw2, cb2, cap_ws, out);
    k_simvote<<<NN, 256, 0, stream>>>(X, y, cap_ws, out);
}

// Round 2
// 159.861 us; speedup vs baseline: 1.0103x; 1.0103x over previous
//
#include <hip/hip_runtime.h>

#define ND 12
#define NN 1024
#define NS 4095
#define NK 32
#define NC 10

// ws layout (floats):
//  [0      .. 4095 ]  cap_ws : unnormalized capacities (zeta output), bitmask-indexed
//  [4096   .. 4351 ]  part   : 16 x 16 latent partial sums
//  [8192   .. 12287]  inc    : increments, bitmask-indexed (inc[0] = 0)
//  [12288  .. +1M  ]  keys   : u32 order-mapped sims, 1024*1024

__global__ __launch_bounds__(64) void k_enc(
    const float* __restrict__ X,
    const float* __restrict__ w1, const float* __restrict__ b1,
    const float* __restrict__ w2, const float* __restrict__ b2,
    const float* __restrict__ lng, const float* __restrict__ lnb,
    const float* __restrict__ w3, const float* __restrict__ b3,
    float* __restrict__ part)
{
    int lane = threadIdx.x;
    int row  = blockIdx.x * 64 + lane;

    float x[ND];
    #pragma unroll
    for (int d = 0; d < ND; ++d) x[d] = X[row * ND + d];

    float h1[32];
    #pragma unroll
    for (int o = 0; o < 32; ++o) {
        float a = b1[o];
        #pragma unroll
        for (int d = 0; d < ND; ++d) a += w1[o * ND + d] * x[d];
        h1[o] = fmaxf(a, 0.f);
    }

    float h2[16];
    #pragma unroll
    for (int o = 0; o < 16; ++o) {
        float a = b2[o];
        #pragma unroll
        for (int k = 0; k < 32; ++k) a += w2[o * 32 + k] * h1[k];
        h2[o] = fmaxf(a, 0.f);
    }

    float mu = 0.f;
    #pragma unroll
    for (int o = 0; o < 16; ++o) mu += h2[o];
    mu *= (1.f / 16.f);
    float var = 0.f;
    #pragma unroll
    for (int o = 0; o < 16; ++o) { float t = h2[o] - mu; var += t * t; }
    var *= (1.f / 16.f);
    float inv = 1.f / sqrtf(var + 1e-5f);

    float hn[16];
    #pragma unroll
    for (int o = 0; o < 16; ++o) hn[o] = (h2[o] - mu) * inv * lng[o] + lnb[o];

    #pragma unroll
    for (int o = 0; o < 16; ++o) {
        float a = b3[o];
        #pragma unroll
        for (int k = 0; k < 16; ++k) a += w3[o * 16 + k] * hn[k];
        // wave-reduce, lane 0 writes the block partial (no atomics, no memset needed)
        #pragma unroll
        for (int s = 1; s < 64; s <<= 1) a += __shfl_xor(a, s, 64);
        if (lane == 0) part[blockIdx.x * 16 + o] = a;
    }
}

__global__ __launch_bounds__(256) void k_inc(
    const float* __restrict__ part,
    const float* __restrict__ cw1, const float* __restrict__ cb1,
    const float* __restrict__ cw2, const float* __restrict__ cb2,
    float* __restrict__ inc)
{
    __shared__ float lat_s[16];
    __shared__ float hc_s[16];
    int tid = threadIdx.x;

    if (tid < 16) {
        float a = 0.f;
        #pragma unroll
        for (int b = 0; b < 16; ++b) a += part[b * 16 + tid];
        lat_s[tid] = a * (1.f / 1024.f);
    }
    __syncthreads();
    if (tid < 16) {
        float a = cb1[tid];
        #pragma unroll
        for (int k = 0; k < 16; ++k) a += cw1[tid * 16 + k] * lat_s[k];
        hc_s[tid] = fmaxf(a, 0.f);
    }
    __syncthreads();

    // each thread handles 4 consecutive floats of cw2 (one quarter-row), coalesced
    int e = blockIdx.x * 1024 + tid * 4;
    int s = e >> 4;
    if (s < NS) {
        float4 w = *reinterpret_cast<const float4*>(cw2 + e);
        int k0 = e & 15;
        float p = w.x * hc_s[k0] + w.y * hc_s[k0 + 1] + w.z * hc_s[k0 + 2] + w.w * hc_s[k0 + 3];
        p += __shfl_xor(p, 1, 64);
        p += __shfl_xor(p, 2, 64);
        if ((tid & 3) == 0) {
            float a = p + cb2[s];
            inc[s + 1] = 0.1f / (1.f + __expf(-a));
        }
    }
    if (blockIdx.x == 0 && tid == 0) inc[0] = 0.f;
}

__global__ __launch_bounds__(1024) void k_zeta(
    const float* __restrict__ inc, float* __restrict__ cap_ws, float* __restrict__ out)
{
    __shared__ float arr[4096];
    int tid = threadIdx.x;

    *reinterpret_cast<float4*>(arr + tid * 4) = *reinterpret_cast<const float4*>(inc + tid * 4);
    __syncthreads();

    #pragma unroll 1
    for (int d = 0; d < ND; ++d) {
        int bit = 1 << d;
        #pragma unroll
        for (int r = 0; r < 2; ++r) {
            int i   = tid + r * 1024;          // 0..2047
            int low = i & (bit - 1);
            int m   = ((i >> d) << (d + 1)) | bit | low;
            arr[m] += arr[m ^ bit];
        }
        __syncthreads();
    }

    float inv = 1.f / (arr[4095] + 1e-8f);
    #pragma unroll
    for (int r = 0; r < 4; ++r) {
        int m = tid * 4 + r;
        cap_ws[m] = arr[m];                       // unnormalized; sims folds inv
        if (m >= 1) out[NN * NC + m - 1] = arr[m] * inv;  // caps output (normalized)
    }
}

#define CSWAP(a,b) { float va=v[a], vb=v[b]; bool sw = va > vb; \
                     v[a]=sw?vb:va; v[b]=sw?va:vb; \
                     int ba=bm[a], bb=bm[b]; bm[a]=sw?bb:ba; bm[b]=sw?ba:bb; }

__global__ __launch_bounds__(256) void k_sims(
    const float* __restrict__ X, const float* __restrict__ cap_ws,
    unsigned* __restrict__ keys)
{
    __shared__ float cap[4096];
    int tid  = threadIdx.x;
    int i    = blockIdx.x >> 1;
    int half = blockIdx.x & 1;

    #pragma unroll
    for (int t = 0; t < 16; ++t) cap[tid + 256 * t] = cap_ws[tid + 256 * t];

    float xi[ND];
    #pragma unroll
    for (int d = 0; d < ND; ++d) xi[d] = X[i * ND + d];
    float inv = 1.f / (cap_ws[4095] + 1e-8f);
    __syncthreads();

    #pragma unroll 1
    for (int t = 0; t < 2; ++t) {
        int j = half * 512 + t * 256 + tid;
        float v[ND]; int bm[ND];
        #pragma unroll
        for (int d = 0; d < ND; ++d) {
            v[d]  = __expf(-fabsf(xi[d] - X[j * ND + d]));
            bm[d] = 1 << d;
        }
        // Batcher odd-even mergesort, 12 inputs, 41 CEs (non-stable: safe, ties
        // give zero-width Choquet terms with a shared tail mask -> sum invariant)
        CSWAP(0,1)  CSWAP(0,2)  CSWAP(1,2)  CSWAP(3,4)  CSWAP(3,5)  CSWAP(4,5)
        CSWAP(0,3)  CSWAP(2,5)  CSWAP(2,3)  CSWAP(1,4)  CSWAP(1,2)  CSWAP(3,4)
        CSWAP(6,7)  CSWAP(6,8)  CSWAP(7,8)  CSWAP(9,10) CSWAP(9,11) CSWAP(10,11)
        CSWAP(6,9)  CSWAP(8,11) CSWAP(8,9)  CSWAP(7,10) CSWAP(7,8)  CSWAP(9,10)
        CSWAP(0,6)  CSWAP(4,10) CSWAP(4,6)  CSWAP(2,8)  CSWAP(2,4)  CSWAP(6,8)
        CSWAP(1,7)  CSWAP(5,11) CSWAP(5,7)  CSWAP(3,9)  CSWAP(3,5)  CSWAP(7,9)
        CSWAP(1,2)  CSWAP(3,4)  CSWAP(5,6)  CSWAP(7,8)  CSWAP(9,10)

        int tail = 0; float sim = 0.f;
        #pragma unroll
        for (int k = ND - 1; k >= 0; --k) {
            tail |= bm[k];
            float pv = (k > 0) ? v[k - 1] : 0.f;
            sim += (v[k] - pv) * cap[tail];
        }
        sim *= inv;

        unsigned u = __float_as_uint(sim);
        u = (u & 0x80000000u) ? ~u : (u | 0x80000000u);  // order-preserving map
        if (j == i) u = 0u;                              // self-exclusion
        keys[i * NN + j] = u;
    }
}

__global__ __launch_bounds__(256) void k_topk(
    const unsigned* __restrict__ keys, const int* __restrict__ y,
    float* __restrict__ out)
{
    __shared__ unsigned long long cand[128];
    __shared__ float bins[NC];
    int tid = threadIdx.x, i = blockIdx.x;
    int wv = tid >> 6, ln = tid & 63;
    if (tid < NC) bins[tid] = 0.f;

    // exact u64 keys: (mapped_val << 10) | (1023 - j)  -> jax lower-index tie-break
    unsigned long long kr[4];
    #pragma unroll
    for (int t = 0; t < 4; ++t) {
        int j = wv * 256 + t * 64 + ln;
        kr[t] = (((unsigned long long)keys[i * NN + j]) << 10) | (unsigned)(1023 - j);
    }

    // phase 1: each wave extracts the top-32 of its 256 keys
    #pragma unroll 1
    for (int it = 0; it < NK; ++it) {
        unsigned long long loc = kr[0];
        #pragma unroll
        for (int t = 1; t < 4; ++t) loc = (kr[t] > loc) ? kr[t] : loc;
        #pragma unroll
        for (int s = 1; s < 64; s <<= 1) {
            unsigned long long o = __shfl_xor(loc, s, 64);
            loc = (o > loc) ? o : loc;
        }
        #pragma unroll
        for (int t = 0; t < 4; ++t) if (kr[t] == loc) kr[t] = 0ull;
        if (ln == it) cand[wv * NK + it] = loc;
    }
    __syncthreads();

    // phase 2: wave 0 merges 128 candidates -> global top-32, then votes
    if (wv == 0) {
        unsigned long long c0 = cand[ln], c1 = cand[64 + ln];
        float selval = 0.f; int selidx = 0;
        #pragma unroll 1
        for (int it = 0; it < NK; ++it) {
            unsigned long long loc = (c1 > c0) ? c1 : c0;
            #pragma unroll
            for (int s = 1; s < 64; s <<= 1) {
                unsigned long long o = __shfl_xor(loc, s, 64);
                loc = (o > loc) ? o : loc;
            }
            if (c0 == loc) c0 = 0ull;
            if (c1 == loc) c1 = 0ull;
            if (ln == it) {
                unsigned su = (unsigned)(loc >> 10);
                unsigned ub = (su & 0x80000000u) ? (su & 0x7FFFFFFFu) : ~su;
                selval = __uint_as_float(ub);
                selidx = 1023 - (int)(loc & 1023ull);
            }
        }
        float vmax = __shfl(selval, 0, 64);
        float w = (ln < NK) ? __expf((selval - vmax) * 2.0f) : 0.f;  // /TEMP, TEMP=0.5
        float sumw = w;
        #pragma unroll
        for (int s = 1; s < 64; s <<= 1) sumw += __shfl_xor(sumw, s, 64);
        float wt = w / sumw;
        if (ln < NK) atomicAdd(&bins[y[selidx]], wt);
        // same-wave LDS ops complete in order; compiler inserts lgkmcnt wait
        if (ln < NC) out[i * NC + ln] = bins[ln];
    }
}

extern "C" void kernel_launch(void* const* d_in, const int* in_sizes, int n_in,
                              void* d_out, int out_size, void* d_ws, size_t ws_size,
                              hipStream_t stream)
{
    const float* X   = (const float*)d_in[0];
    const int*   y   = (const int*)  d_in[1];
    const float* w1  = (const float*)d_in[2];
    const float* b1  = (const float*)d_in[3];
    const float* w2  = (const float*)d_in[4];
    const float* b2  = (const float*)d_in[5];
    const float* lng = (const float*)d_in[6];
    const float* lnb = (const float*)d_in[7];
    const float* w3  = (const float*)d_in[8];
    const float* b3  = (const float*)d_in[9];
    const float* cw1 = (const float*)d_in[10];
    const float* cb1 = (const float*)d_in[11];
    const float* cw2 = (const float*)d_in[12];
    const float* cb2 = (const float*)d_in[13];
    float* out = (float*)d_out;
    float* ws  = (float*)d_ws;

    float*    cap_ws = ws;                     // 4096 floats
    float*    part   = ws + 4096;              // 256 floats
    float*    inc    = ws + 8192;              // 4096 floats
    unsigned* keys   = (unsigned*)(ws + 12288); // 1024*1024 u32

    k_enc <<<16,   64,   0, stream>>>(X, w1, b1, w2, b2, lng, lnb, w3, b3, part);
    k_inc <<<64,   256,  0, stream>>>(part, cw1, cb1, cw2, cb2, inc);
    k_zeta<<<1,    1024, 0, stream>>>(inc, cap_ws, out);
    k_sims<<<2048, 256,  0, stream>>>(X, cap_ws, keys);
    k_topk<<<1024, 256,  0, stream>>>(keys, y, out);
}

// Round 3
// 126.622 us; speedup vs baseline: 1.2755x; 1.2625x over previous
//
#include <hip/hip_runtime.h>

#define ND 12
#define NN 1024
#define NS 4095
#define NK 32
#define NC 10

// ws layout (floats):
//  [0    .. 4095]  cap_ws : unnormalized capacities (zeta output), bitmask-indexed
//  [4096 .. 4351]  part   : 16 x 16 latent partial sums
//  [8192 .. 12287] inc    : increments, bitmask-indexed (inc[0] = 0)

__global__ __launch_bounds__(64) void k_enc(
    const float* __restrict__ X,
    const float* __restrict__ w1, const float* __restrict__ b1,
    const float* __restrict__ w2, const float* __restrict__ b2,
    const float* __restrict__ lng, const float* __restrict__ lnb,
    const float* __restrict__ w3, const float* __restrict__ b3,
    float* __restrict__ part)
{
    int lane = threadIdx.x;
    int row  = blockIdx.x * 64 + lane;

    float x[ND];
    #pragma unroll
    for (int d = 0; d < ND; ++d) x[d] = X[row * ND + d];

    float h1[32];
    #pragma unroll
    for (int o = 0; o < 32; ++o) {
        float a = b1[o];
        #pragma unroll
        for (int d = 0; d < ND; ++d) a += w1[o * ND + d] * x[d];
        h1[o] = fmaxf(a, 0.f);
    }

    float h2[16];
    #pragma unroll
    for (int o = 0; o < 16; ++o) {
        float a = b2[o];
        #pragma unroll
        for (int k = 0; k < 32; ++k) a += w2[o * 32 + k] * h1[k];
        h2[o] = fmaxf(a, 0.f);
    }

    float mu = 0.f;
    #pragma unroll
    for (int o = 0; o < 16; ++o) mu += h2[o];
    mu *= (1.f / 16.f);
    float var = 0.f;
    #pragma unroll
    for (int o = 0; o < 16; ++o) { float t = h2[o] - mu; var += t * t; }
    var *= (1.f / 16.f);
    float inv = 1.f / sqrtf(var + 1e-5f);

    float hn[16];
    #pragma unroll
    for (int o = 0; o < 16; ++o) hn[o] = (h2[o] - mu) * inv * lng[o] + lnb[o];

    #pragma unroll
    for (int o = 0; o < 16; ++o) {
        float a = b3[o];
        #pragma unroll
        for (int k = 0; k < 16; ++k) a += w3[o * 16 + k] * hn[k];
        #pragma unroll
        for (int s = 1; s < 64; s <<= 1) a += __shfl_xor(a, s, 64);
        if (lane == 0) part[blockIdx.x * 16 + o] = a;
    }
}

__global__ __launch_bounds__(256) void k_inc(
    const float* __restrict__ part,
    const float* __restrict__ cw1, const float* __restrict__ cb1,
    const float* __restrict__ cw2, const float* __restrict__ cb2,
    float* __restrict__ inc)
{
    __shared__ float lat_s[16];
    __shared__ float hc_s[16];
    int tid = threadIdx.x;

    if (tid < 16) {
        float a = 0.f;
        #pragma unroll
        for (int b = 0; b < 16; ++b) a += part[b * 16 + tid];
        lat_s[tid] = a * (1.f / 1024.f);
    }
    __syncthreads();
    if (tid < 16) {
        float a = cb1[tid];
        #pragma unroll
        for (int k = 0; k < 16; ++k) a += cw1[tid * 16 + k] * lat_s[k];
        hc_s[tid] = fmaxf(a, 0.f);
    }
    __syncthreads();

    int e = blockIdx.x * 1024 + tid * 4;
    int s = e >> 4;
    if (s < NS) {
        float4 w = *reinterpret_cast<const float4*>(cw2 + e);
        int k0 = e & 15;
        float p = w.x * hc_s[k0] + w.y * hc_s[k0 + 1] + w.z * hc_s[k0 + 2] + w.w * hc_s[k0 + 3];
        p += __shfl_xor(p, 1, 64);
        p += __shfl_xor(p, 2, 64);
        if ((tid & 3) == 0) {
            float a = p + cb2[s];
            inc[s + 1] = 0.1f / (1.f + __expf(-a));
        }
    }
    if (blockIdx.x == 0 && tid == 0) inc[0] = 0.f;
}

__global__ __launch_bounds__(1024) void k_zeta(
    const float* __restrict__ inc, float* __restrict__ cap_ws, float* __restrict__ out)
{
    __shared__ float arr[4096];
    int tid = threadIdx.x;

    *reinterpret_cast<float4*>(arr + tid * 4) = *reinterpret_cast<const float4*>(inc + tid * 4);
    __syncthreads();

    #pragma unroll 1
    for (int d = 0; d < ND; ++d) {
        int bit = 1 << d;
        #pragma unroll
        for (int r = 0; r < 2; ++r) {
            int i   = tid + r * 1024;
            int low = i & (bit - 1);
            int m   = ((i >> d) << (d + 1)) | bit | low;
            arr[m] += arr[m ^ bit];
        }
        __syncthreads();
    }

    float inv = 1.f / (arr[4095] + 1e-8f);
    #pragma unroll
    for (int r = 0; r < 4; ++r) {
        int m = tid * 4 + r;
        cap_ws[m] = arr[m];
        if (m >= 1) out[NN * NC + m - 1] = arr[m] * inv;
    }
}

#define CSWAP(a,b) { float va=v[a], vb=v[b]; bool sw = va > vb; \
                     v[a]=sw?vb:va; v[b]=sw?va:vb; \
                     int ba=bm[a], bb=bm[b]; bm[a]=sw?bb:ba; bm[b]=sw?ba:bb; }

// Fused: per-row sims (4/thread, registers) + exact top-32 via 42-bit radix
// select (no serial K-loop; softmax-vote is permutation-invariant so we only
// need the SET, tie-break = jax lower-index via key = mapped<<10 | (1023-j))
__global__ __launch_bounds__(256) void k_simsel(
    const float* __restrict__ X, const int* __restrict__ y,
    const float* __restrict__ cap_ws, float* __restrict__ out)
{
    __shared__ float    cap[4096];     // 16 KB
    __shared__ unsigned bins[2048];    // 8 KB
    __shared__ unsigned wt_u[4];
    __shared__ unsigned ctl_bin, ctl_need;
    __shared__ unsigned vmax_u[4];
    __shared__ float    wsum_s[4];
    __shared__ float    fbins[NC];

    int tid = threadIdx.x, i = blockIdx.x;
    int wv = tid >> 6, ln = tid & 63;

    #pragma unroll
    for (int t = 0; t < 16; ++t) cap[tid + 256 * t] = cap_ws[tid + 256 * t];

    float xi[ND];
    #pragma unroll
    for (int d = 0; d < ND; ++d) xi[d] = X[i * ND + d];
    float inv = 1.f / (cap_ws[4095] + 1e-8f);
    __syncthreads();

    // ---- sims: 4 pairs per thread, keys in registers ----
    unsigned long long kreg[4];
    #pragma unroll
    for (int t = 0; t < 4; ++t) {
        int j = t * 256 + tid;
        float v[ND]; int bm[ND];
        #pragma unroll
        for (int d = 0; d < ND; ++d) {
            v[d]  = __expf(-fabsf(xi[d] - X[j * ND + d]));
            bm[d] = 1 << d;
        }
        // Batcher odd-even mergesort, 12 inputs, 41 CEs
        CSWAP(0,1)  CSWAP(0,2)  CSWAP(1,2)  CSWAP(3,4)  CSWAP(3,5)  CSWAP(4,5)
        CSWAP(0,3)  CSWAP(2,5)  CSWAP(2,3)  CSWAP(1,4)  CSWAP(1,2)  CSWAP(3,4)
        CSWAP(6,7)  CSWAP(6,8)  CSWAP(7,8)  CSWAP(9,10) CSWAP(9,11) CSWAP(10,11)
        CSWAP(6,9)  CSWAP(8,11) CSWAP(8,9)  CSWAP(7,10) CSWAP(7,8)  CSWAP(9,10)
        CSWAP(0,6)  CSWAP(4,10) CSWAP(4,6)  CSWAP(2,8)  CSWAP(2,4)  CSWAP(6,8)
        CSWAP(1,7)  CSWAP(5,11) CSWAP(5,7)  CSWAP(3,9)  CSWAP(3,5)  CSWAP(7,9)
        CSWAP(1,2)  CSWAP(3,4)  CSWAP(5,6)  CSWAP(7,8)  CSWAP(9,10)

        int tail = 0; float sim = 0.f;
        #pragma unroll
        for (int k = ND - 1; k >= 0; --k) {
            tail |= bm[k];
            float pv = (k > 0) ? v[k - 1] : 0.f;
            sim += (v[k] - pv) * cap[tail];
        }
        sim *= inv;

        unsigned u = __float_as_uint(sim);
        u = (u & 0x80000000u) ? ~u : (u | 0x80000000u);
        if (j == i) u = 0u;
        kreg[t] = (((unsigned long long)u) << 10) | (unsigned)(1023 - j);
    }

    // ---- block max of mapped values (softmax stabilizer = top-1 sim) ----
    unsigned mv = 0;
    #pragma unroll
    for (int t = 0; t < 4; ++t) {
        unsigned x = (unsigned)(kreg[t] >> 10);
        mv = (x > mv) ? x : mv;
    }
    #pragma unroll
    for (int s = 1; s < 64; s <<= 1) {
        unsigned o = __shfl_xor(mv, s, 64);
        mv = (o > mv) ? o : mv;
    }
    if (ln == 0) vmax_u[wv] = mv;

    // ---- radix select: find 32nd-largest 42-bit key ----
    unsigned long long prefix = 0;
    unsigned need = NK;
    #pragma unroll 1
    for (int lev = 0; lev < 4; ++lev) {
        int shift   = (lev < 3) ? (31 - 11 * lev) : 0;
        int bits    = (lev < 3) ? 11 : 9;
        int topbits = shift + bits;
        unsigned mask = (1u << bits) - 1u;

        #pragma unroll
        for (int r = 0; r < 8; ++r) bins[tid + 256 * r] = 0u;
        __syncthreads();

        #pragma unroll
        for (int t = 0; t < 4; ++t) {
            unsigned long long k = kreg[t];
            if ((k >> topbits) == prefix)
                atomicAdd(&bins[(unsigned)(k >> shift) & mask], 1u);
        }
        __syncthreads();

        // per-thread chunk of 8 bins; suffix-scan from the top
        unsigned s8[8]; unsigned S = 0;
        int base = tid * 8;
        #pragma unroll
        for (int r = 0; r < 8; ++r) { s8[r] = bins[base + r]; S += s8[r]; }
        unsigned v = S;
        #pragma unroll
        for (int off = 1; off < 64; off <<= 1) {
            unsigned o = __shfl_down(v, off, 64);
            if (ln + off < 64) v += o;
        }
        if (ln == 0) wt_u[wv] = v;   // wave total
        __syncthreads();
        unsigned G = v - S;          // lanes above within wave
        #pragma unroll
        for (int w2 = 0; w2 < 4; ++w2) if (w2 > wv) G += wt_u[w2];

        unsigned cum = G;
        #pragma unroll
        for (int r = 7; r >= 0; --r) {
            unsigned c = s8[r];
            if (cum < need && cum + c >= need) { ctl_bin = (unsigned)(base + r); ctl_need = need - cum; }
            cum += c;
        }
        __syncthreads();
        prefix = (prefix << bits) | ctl_bin;
        need   = ctl_need;
        __syncthreads();
    }
    unsigned long long T = prefix;   // exact 32nd-largest key

    // ---- softmax weights over the selected set + vote ----
    unsigned m0 = vmax_u[0], m1 = vmax_u[1], m2 = vmax_u[2], m3 = vmax_u[3];
    mv = (m1 > m0) ? m1 : m0;
    mv = (m2 > mv) ? m2 : mv;
    mv = (m3 > mv) ? m3 : mv;
    float vmax = (mv & 0x80000000u) ? __uint_as_float(mv & 0x7fffffffu) : __uint_as_float(~mv);

    float wr[4]; float wpart = 0.f;
    #pragma unroll
    for (int t = 0; t < 4; ++t) {
        bool sel = kreg[t] >= T;
        unsigned su = (unsigned)(kreg[t] >> 10);
        float val = (su & 0x80000000u) ? __uint_as_float(su & 0x7fffffffu) : __uint_as_float(~su);
        float w = __expf((val - vmax) * 2.0f);   // /TEMP, TEMP=0.5
        w = sel ? w : 0.f;
        wr[t] = w; wpart += w;
    }
    #pragma unroll
    for (int s = 1; s < 64; s <<= 1) wpart += __shfl_xor(wpart, s, 64);
    if (ln == 0) wsum_s[wv] = wpart;
    if (tid < NC) fbins[tid] = 0.f;
    __syncthreads();
    float wsum = wsum_s[0] + wsum_s[1] + wsum_s[2] + wsum_s[3];
    #pragma unroll
    for (int t = 0; t < 4; ++t)
        if (wr[t] != 0.f) atomicAdd(&fbins[y[t * 256 + tid]], wr[t]);
    __syncthreads();
    if (tid < NC) out[i * NC + tid] = fbins[tid] / wsum;
}

extern "C" void kernel_launch(void* const* d_in, const int* in_sizes, int n_in,
                              void* d_out, int out_size, void* d_ws, size_t ws_size,
                              hipStream_t stream)
{
    const float* X   = (const float*)d_in[0];
    const int*   y   = (const int*)  d_in[1];
    const float* w1  = (const float*)d_in[2];
    const float* b1  = (const float*)d_in[3];
    const float* w2  = (const float*)d_in[4];
    const float* b2  = (const float*)d_in[5];
    const float* lng = (const float*)d_in[6];
    const float* lnb = (const float*)d_in[7];
    const float* w3  = (const float*)d_in[8];
    const float* b3  = (const float*)d_in[9];
    const float* cw1 = (const float*)d_in[10];
    const float* cb1 = (const float*)d_in[11];
    const float* cw2 = (const float*)d_in[12];
    const float* cb2 = (const float*)d_in[13];
    float* out = (float*)d_out;
    float* ws  = (float*)d_ws;

    float* cap_ws = ws;         // 4096 floats
    float* part   = ws + 4096;  // 256 floats
    float* inc    = ws + 8192;  // 4096 floats

    k_enc   <<<16,   64,   0, stream>>>(X, w1, b1, w2, b2, lng, lnb, w3, b3, part);
    k_inc   <<<64,   256,  0, stream>>>(part, cw1, cb1, cw2, cb2, inc);
    k_zeta  <<<1,    1024, 0, stream>>>(inc, cap_ws, out);
    k_simsel<<<NN,   256,  0, stream>>>(X, y, cap_ws, out);
}